// Round 12
// baseline (5990.117 us; speedup 1.0000x reference)
//
#include <hip/hip_runtime.h>
#include <math.h>

#pragma clang fp contract(off)

#define BB 64      // batch
#define N_IN 64
#define N_E 256
#define N_I 64
#define N_OUT 10

__device__ inline unsigned long long rfl64(unsigned long long x) {
  unsigned int lo = __builtin_amdgcn_readfirstlane((unsigned int)x);
  unsigned int hi = __builtin_amdgcn_readfirstlane((unsigned int)(x >> 32));
  return (((unsigned long long)hi) << 32) | (unsigned long long)lo;
}

// r11 (bit-exact, 5.30 ms) with the two data-dependent LDS gathers
// SOFTWARE-PIPELINED off the serial cross-wave cycle:
//  - kie loads issue right after the I-LIF ballot (mI just computed, end of
//    iter t), summed at iter t+1 -> latency overlaps O-LIF + back-edge.
//  - pEI/kow loads issue right after the E-LIF ballot (mE just computed,
//    mid-iter t), summed at iter end into pipeline regs, published at iter
//    t+1 top -> latency overlaps W0-prefetch + poll + I-LIF.
//  - W0 prefetch moved before the poll (independent of partials).
// The publish/poll protocol is UNCHANGED from r11 (publish slot t&1 at iter
// top -> poll -> read same slot; proven race-free by induction) — only load
// issue points move. Remainder loops (>8 I-spikes, >6 E-word spikes) keep
// ascending order; all fp accumulation orders byte-identical to r11.
__global__ __launch_bounds__(256, 1) void ping_kernel(
    const float* __restrict__ g_in,   // [T,64,64]
    const float* __restrict__ g_W0,   // [64,256]  clamp >=0 at use
    const float* __restrict__ g_W1,   // [256,10]  clamp >=0 at stage
    const float* __restrict__ g_Wee,  // [256,256]
    const float* __restrict__ g_Wei,  // [256,64]
    const float* __restrict__ g_Wie,  // [64,256]
    float* __restrict__ g_out,        // [64,10]
    int T, float dA, float dG)
{
  const int tid  = threadIdx.x;
  const int lane = tid & 63;
  const int wav  = tid >> 6;
  const int b    = blockIdx.x;
  const int col  = (lane < N_OUT) ? lane : 0;

  __shared__ float sWie[N_I * N_E];          // 64 KB  [j][e]
  __shared__ float sWei[N_E * N_I];          // 64 KB  [j][i]
  __shared__ float sW1[N_E * N_OUT];         // 10 KB  [j][o], clamped
  __shared__ float sZeroRow[256];            // 1 KB zero row
  __shared__ float sP[2][4][64];             // E->I word partials (slot t&1)
  __shared__ float sKo[2][4][16];            // E->O word partials (slot t&1)
  __shared__ unsigned sTag[2][4];            // publish tags (slot t&1)
  __shared__ unsigned long long sME[2][4];   // E masks (wee fallback only)
  __shared__ int sWee;

  // ---- one-time staging ----
  {
    const float4* s0 = (const float4*)g_Wie; float4* d0 = (float4*)sWie;
    for (int k = tid; k < (N_I * N_E) / 4; k += 256) d0[k] = s0[k];
    const float4* s1 = (const float4*)g_Wei; float4* d1 = (float4*)sWei;
    for (int k = tid; k < (N_E * N_I) / 4; k += 256) d1[k] = s1[k];
    for (int k = tid; k < N_E * N_OUT; k += 256) sW1[k] = fmaxf(g_W1[k], 0.f);
  }
  sZeroRow[tid] = 0.f;
  if (tid < 4) { sME[0][tid] = 0ull; sME[1][tid] = 0ull; }
  if (tid < 8) sTag[tid >> 2][tid & 3] = 0u;
  if (tid == 0) sWee = 0;
  // detect all-zero W_ee (true for this data; skipping a zero matmul is fp-exact)
  {
    bool any = false;
    const float4* p = (const float4*)g_Wee;
    for (int k = tid; k < (N_E * N_E) / 4; k += 256) {
      float4 x = p[k];
      any |= (x.x != 0.f) | (x.y != 0.f) | (x.z != 0.f) | (x.w != 0.f);
    }
    if (__ballot(any) != 0ull && lane == 0) sWee = 1;
  }
  __syncthreads();
  const int wee = sWee;

  // ---- per-thread state ----
  float vE = -65.f, ge = 0.f, gi = 0.f; int rE = 0;     // E neuron = tid
  float vI = -65.f, gI = 0.f; int rI = 0;               // I neuron = lane (replicated)
  float vO = -65.f, gO = 0.f, accO = 0.f; int rO = 0;   // output (replicated)

  unsigned long long mE = 0ull;   // own E word, s_e(t-1) (wave-local)
  unsigned long long mI = 0ull;   // I mask, s_i(t-1) (replicated in-register)
  unsigned long long we0 = 0ull, we1 = 0ull, we2 = 0ull, we3 = 0ull;  // wee only

  // ---- pipeline registers ----
  float pEI_nx = 0.f, kow_nx = 0.f;     // partials over s_e(t-1), publish at iter t
  float kieF[8] = {0,0,0,0,0,0,0,0};    // prefetched kie loads (mI(t-1))
  unsigned long long kieRem = 0ull;     // kie remainder mask (>8 I-spikes)

  // input + W0 prefetch pipeline
  float cur = g_in[b * N_IN + lane];
  float n1  = g_in[((T > 1 ? 1 : 0) * BB + b) * N_IN + lane];

  unsigned long long mInC = __ballot(cur != 0.f);
  unsigned long long aRemC = 0ull;
  bool vaC[4] = {false, false, false, false};
  float fwC[4];
  if (mInC) {
    unsigned long long a = mInC;
    int ja[4];
#pragma unroll
    for (int k = 0; k < 4; ++k) {
      vaC[k] = (a != 0ull); ja[k] = vaC[k] ? (__ffsll(a) - 1) : 0; a &= (a - 1ull);
    }
    aRemC = a;
#pragma unroll
    for (int k = 0; k < 4; ++k) fwC[k] = g_W0[ja[k] * N_E + tid];
  }

  for (int t = 0; t < T; ++t) {
    const int slot = t & 1;
    const int tp = (t + 2 < T) ? (t + 2) : (T - 1);
    float n2 = g_in[(tp * BB + b) * N_IN + lane];   // prefetch t+2

    // ---- 1. publish pipelined partials + tag (r11 slot protocol) ----
    sP[slot][wav][lane] = pEI_nx;
    if (lane < 16) sKo[slot][wav][lane] = kow_nx;
    asm volatile("s_waitcnt lgkmcnt(0)" ::: "memory");
    if (lane == 0) *((volatile unsigned*)&sTag[slot][wav]) = (unsigned)(t + 1);

    // ---- 2. consume prefetched kie + remainder (ascending) ----
    float kie = 0.f;
#pragma unroll
    for (int k = 0; k < 8; ++k) kie += kieF[k];
    while (kieRem) {
      const float* pb[4];
#pragma unroll
      for (int k = 0; k < 4; ++k) {
        bool v = (kieRem != 0ull); int j = v ? (__ffsll(kieRem) - 1) : 0; kieRem &= (kieRem - 1ull);
        pb[k] = v ? &sWie[j * N_E] : sZeroRow;
      }
      float fI[4];
#pragma unroll
      for (int k = 0; k < 4; ++k) fI[k] = pb[k][tid];
#pragma unroll
      for (int k = 0; k < 4; ++k) kie += fI[k];
    }

    // ---- 3. consume W0 (prefetched last iter; ascending) ----
    float kin = 0.f;
    if (mInC) {
#pragma unroll
      for (int k = 0; k < 4; ++k) kin += vaC[k] ? fmaxf(fwC[k], 0.f) : 0.f;
      while (aRemC) {
        int j = __ffsll(aRemC) - 1; aRemC &= (aRemC - 1ull);
        kin += fmaxf(g_W0[j * N_E + tid], 0.f);
      }
    }

    // ---- 4. E<-E fallback (dead for this data) ----
    float kee = 0.f;
    if (wee) {
      unsigned long long m0 = we0, m1 = we1, m2 = we2, m3 = we3;
      while (m0 | m1 | m2 | m3) {
        bool h0 = (m0 != 0ull), h1 = (m1 != 0ull), h2 = (m2 != 0ull), h3 = (m3 != 0ull);
        int idx = 0;
        if (h0)      { idx = __ffsll(m0) - 1;       m0 &= (m0 - 1ull); }
        else if (h1) { idx = 64 + __ffsll(m1) - 1;  m1 &= (m1 - 1ull); }
        else if (h2) { idx = 128 + __ffsll(m2) - 1; m2 &= (m2 - 1ull); }
        else if (h3) { idx = 192 + __ffsll(m3) - 1; m3 &= (m3 - 1ull); }
        kee += g_Wee[idx * N_E + tid];
      }
    }

    // ---- 5. E LIF (COBA, C_m=1, g_L=0.05, ref=12) -> mE(t) ----
    ge = ((ge + kin) + kee) * dA;
    gi = (gi + kie) * dG;
    {
      float t2 = ge * (0.f - vE);
      float t3 = gi * (-80.f - vE);
      float Itot = t2 + t3;
      float dv = 0.25f * ((-0.05f) * (vE - (-65.f)) + Itot);
      dv = dv * 0.0125f + dv * 0.9875f;      // _scale_grad forward (not fp-identity)
      vE = fmaxf(vE + dv, -200.f);
      rE = rE - 1; if (rE < 0) rE = 0;
      bool can = (rE == 0);
      bool sE = ((vE - (-50.f)) >= 0.f) && can;
      vE = (sE || !can) ? -65.f : vE;
      rE = sE ? 12 : rE;
      unsigned long long fresh = __ballot(sE);
      if (wee && lane == 0) sME[slot][wav] = fresh;
      mE = fresh;
    }

    // ---- 6. ISSUE E-word gather over mE(t) (6 slots; sum at iter end) ----
    float fqN[6], frN[6];
    unsigned long long eRem;
    {
      unsigned long long e = mE;
      const int base = wav * 64;
      const float *qb[6], *rb[6];
#pragma unroll
      for (int k = 0; k < 6; ++k) {
        bool v = (e != 0ull); int j = v ? (__ffsll(e) - 1) : 0; e &= (e - 1ull);
        qb[k] = v ? &sWei[(base + j) * N_I] : sZeroRow;
        rb[k] = v ? &sW1[(base + j) * N_OUT] : sZeroRow;
      }
      eRem = e;
#pragma unroll
      for (int k = 0; k < 6; ++k) { fqN[k] = qb[k][lane]; frN[k] = rb[k][col]; }
    }

    // ---- 7. W0 prefetch for t+1 (independent of partials) ----
    mInC = __ballot(n1 != 0.f);
    aRemC = 0ull;
    vaC[0] = vaC[1] = vaC[2] = vaC[3] = false;
    if (mInC) {
      unsigned long long a = mInC;
      int ja[4];
#pragma unroll
      for (int k = 0; k < 4; ++k) {
        vaC[k] = (a != 0ull); ja[k] = vaC[k] ? (__ffsll(a) - 1) : 0; a &= (a - 1ull);
      }
      aRemC = a;
#pragma unroll
      for (int k = 0; k < 4; ++k) fwC[k] = g_W0[ja[k] * N_E + tid];
    }

    // ---- 8. poll tags (published early; first read should hit) ----
    {
      const unsigned want = (unsigned)(t + 1);
      volatile unsigned* vt = &sTag[slot][0];
      while (true) {
        unsigned a0 = vt[0], a1 = vt[1], a2 = vt[2], a3 = vt[3];
        if ((((a0 ^ want) | (a1 ^ want)) | ((a2 ^ want) | (a3 ^ want))) == 0u) break;
      }
      asm volatile("" ::: "memory");
    }

    // ---- 9. read partials ----
    float p0 = sP[slot][0][lane], p1 = sP[slot][1][lane];
    float p2 = sP[slot][2][lane], p3 = sP[slot][3][lane];
    float k0 = sKo[slot][0][col], k1 = sKo[slot][1][col];
    float k2 = sKo[slot][2][col], k3 = sKo[slot][3][col];

    // ---- 10. I LIF (replicated; C_m=0.5, g_L=0.1, ref=6) -> mI(t) ----
    {
      float p = ((p0 + p1) + p2) + p3;
      gI = (gI + p) * dA;
      float Ii = gI * (0.f - vI);
      float dvi = 0.5f * ((-0.1f) * (vI - (-65.f)) + Ii);
      dvi = dvi * 0.0125f + dvi * 0.9875f;
      vI = fmaxf(vI + dvi, -200.f);
      rI = rI - 1; if (rI < 0) rI = 0;
      bool canI = (rI == 0);
      bool sI = ((vI - (-50.f)) >= 0.f) && canI;
      vI = (sI || !canI) ? -65.f : vI;
      rI = sI ? 6 : rI;
      mI = __ballot(sI);
    }

    // ---- 11. ISSUE kie prefetch over mI(t) (8 slots; sum next iter) ----
    {
      unsigned long long c = mI;
      const float* pb[8];
#pragma unroll
      for (int k = 0; k < 8; ++k) {
        bool v = (c != 0ull); int j = v ? (__ffsll(c) - 1) : 0; c &= (c - 1ull);
        pb[k] = v ? &sWie[j * N_E] : sZeroRow;
      }
      kieRem = c;
#pragma unroll
      for (int k = 0; k < 8; ++k) kieF[k] = pb[k][tid];
    }

    // ---- 12. O LIF (replicated, step t-1; iter 0 = exact fp no-op) ----
    {
      float ko = ((k0 + k1) + k2) + k3;
      gO = (gO + ko) * dA;
      float Io = gO * (0.f - vO);
      float dvo = 0.25f * ((-0.05f) * (vO - (-65.f)) + Io);
      dvo = dvo * 0.0125f + dvo * 0.9875f;
      vO = fmaxf(vO + dvo, -200.f);
      rO = rO - 1; if (rO < 0) rO = 0;
      bool canO = (rO == 0);
      bool sO = ((vO - (-50.f)) >= 0.f) && canO;
      vO = (sO || !canO) ? -65.f : vO;
      rO = sO ? 12 : rO;
      accO += sO ? 1.f : 0.f;
    }

    if (wee) {
      __syncthreads();   // fallback-only (dead path here)
      we0 = rfl64(sME[slot][0]); we1 = rfl64(sME[slot][1]);
      we2 = rfl64(sME[slot][2]); we3 = rfl64(sME[slot][3]);
    }

    // ---- 13. sum E-word gather -> pipeline regs (+ remainder, ascending) ----
    {
      float pe = 0.f, ko2 = 0.f;
#pragma unroll
      for (int k = 0; k < 6; ++k) pe += fqN[k];
#pragma unroll
      for (int k = 0; k < 6; ++k) ko2 += frN[k];
      const int base = wav * 64;
      while (eRem) {
        const float *qb[4], *rb[4];
#pragma unroll
        for (int k = 0; k < 4; ++k) {
          bool v = (eRem != 0ull); int j = v ? (__ffsll(eRem) - 1) : 0; eRem &= (eRem - 1ull);
          qb[k] = v ? &sWei[(base + j) * N_I] : sZeroRow;
          rb[k] = v ? &sW1[(base + j) * N_OUT] : sZeroRow;
        }
        float fq[4], fr[4];
#pragma unroll
        for (int k = 0; k < 4; ++k) { fq[k] = qb[k][lane]; fr[k] = rb[k][col]; }
#pragma unroll
        for (int k = 0; k < 4; ++k) pe += fq[k];
#pragma unroll
        for (int k = 0; k < 4; ++k) ko2 += fr[k];
      }
      pEI_nx = pe; kow_nx = ko2;
    }

    cur = n1; n1 = n2;
  }

  // ---- drain: O step T-1 over s_e(T-1) (own word in mE) ----
  {
    float kd = 0.f;
    unsigned long long e = mE;
    const int base = wav * 64;
    while (e) {
      const float* rb[4];
#pragma unroll
      for (int k = 0; k < 4; ++k) {
        bool v = (e != 0ull); int j = v ? (__ffsll(e) - 1) : 0; e &= (e - 1ull);
        rb[k] = v ? &sW1[(base + j) * N_OUT] : sZeroRow;
      }
      float fr[4];
#pragma unroll
      for (int k = 0; k < 4; ++k) fr[k] = rb[k][col];
#pragma unroll
      for (int k = 0; k < 4; ++k) kd += fr[k];
    }
    __syncthreads();
    sP[0][wav][lane] = kd;
    __syncthreads();
    float ko = ((sP[0][0][col] + sP[0][1][col]) + sP[0][2][col]) + sP[0][3][col];
    gO = (gO + ko) * dA;
    float Io = gO * (0.f - vO);
    float dvo = 0.25f * ((-0.05f) * (vO - (-65.f)) + Io);
    dvo = dvo * 0.0125f + dvo * 0.9875f;
    vO = fmaxf(vO + dvo, -200.f);
    rO = rO - 1; if (rO < 0) rO = 0;
    bool canO = (rO == 0);
    bool sO = ((vO - (-50.f)) >= 0.f) && canO;
    accO += sO ? 1.f : 0.f;
  }

  if (wav == 0 && lane < N_OUT) g_out[b * N_OUT + lane] = accO;
}

extern "C" void kernel_launch(void* const* d_in, const int* in_sizes, int n_in,
                              void* d_out, int out_size, void* d_ws, size_t ws_size,
                              hipStream_t stream) {
  const float* g_in  = (const float*)d_in[0];
  const float* g_W0  = (const float*)d_in[1];
  const float* g_W1  = (const float*)d_in[2];
  const float* g_Wee = (const float*)d_in[3];
  const float* g_Wei = (const float*)d_in[4];
  const float* g_Wie = (const float*)d_in[5];
  float* out = (float*)d_out;
  int T = in_sizes[0] / (BB * N_IN);
  float dA = (float)exp(-0.25 / 2.0);   // tau_ampa = 2.0
  float dG = (float)exp(-0.25 / 9.0);   // tau_gaba = 9.0
  ping_kernel<<<dim3(BB), dim3(256), 0, stream>>>(g_in, g_W0, g_W1, g_Wee, g_Wei, g_Wie, out, T, dA, dG);
}

// Round 13
// 4890.738 us; speedup vs baseline: 1.2248x; 1.2248x over previous
//
#include <hip/hip_runtime.h>
#include <math.h>

#pragma clang fp contract(off)

#define BB 64      // batch
#define N_IN 64
#define N_E 256
#define N_I 64
#define N_OUT 10

__device__ inline unsigned long long rfl64(unsigned long long x) {
  unsigned int lo = __builtin_amdgcn_readfirstlane((unsigned int)x);
  unsigned int hi = __builtin_amdgcn_readfirstlane((unsigned int)(x >> 32));
  return (((unsigned long long)hi) << 32) | (unsigned long long)lo;
}

// r11 (bit-exact, 5.30 ms) with an instruction diet. r12 proved per-step time
// tracks the per-wave body instruction count (~2.4 ns/instr; compiler already
// hides LDS latency inside the body). Diet:
//  (1) merged Wei||W1 table sWeiO[256][80] (cols 0-63 Wei, 64-73 clamped W1):
//      ONE base select per E-slot serves both gathers.
//  (2) hot loop carries zero wee code (fallback loop = full r11 body).
//  (3) poll via 2 x b64 volatile reads of the 16B-aligned tag quad.
// Publish/poll protocol, slot buffering, gather orders, LIF sequences are
// byte-identical to r11 (ascending within word, ((x0+x1)+x2)+x3 combines,
// zero-row +0.0f, delayed-O, W0 bottom prefetch).
__global__ __launch_bounds__(256, 1) void ping_kernel(
    const float* __restrict__ g_in,   // [T,64,64]
    const float* __restrict__ g_W0,   // [64,256]  clamp >=0 at use
    const float* __restrict__ g_W1,   // [256,10]  clamp >=0 at stage
    const float* __restrict__ g_Wee,  // [256,256]
    const float* __restrict__ g_Wei,  // [256,64]
    const float* __restrict__ g_Wie,  // [64,256]
    float* __restrict__ g_out,        // [64,10]
    int T, float dA, float dG)
{
  const int tid  = threadIdx.x;
  const int lane = tid & 63;
  const int wav  = tid >> 6;
  const int b    = blockIdx.x;
  const int col  = (lane < N_OUT) ? lane : 0;
  const int colO = 64 + col;                 // W1 column inside merged row

  __shared__ float sWie[N_I * N_E];          // 64 KB  [j][e]
  __shared__ float sWeiO[N_E * 80];          // 80 KB  [j][0:64)=Wei, [64:74)=W1
  __shared__ float sZeroRow[256];            // 1 KB zero row (serves both gathers)
  __shared__ float sP[2][4][64];             // E->I word partials (slot t&1)
  __shared__ float sKo[2][4][16];            // E->O word partials (slot t&1)
  __shared__ __align__(16) unsigned sTag[2][4];  // publish tags (16B quads)
  __shared__ unsigned long long sME[2][4];   // E masks (wee fallback only)
  __shared__ int sWee;

  // ---- one-time staging ----
  {
    const float4* s0 = (const float4*)g_Wie; float4* d0 = (float4*)sWie;
    for (int k = tid; k < (N_I * N_E) / 4; k += 256) d0[k] = s0[k];
    // merged table: one row per thread (256 threads, 256 rows)
    {
      int j = tid;
      float* row = &sWeiO[j * 80];
      for (int c = 0; c < 64; ++c) row[c] = g_Wei[j * N_I + c];
      for (int o = 0; o < N_OUT; ++o) row[64 + o] = fmaxf(g_W1[j * N_OUT + o], 0.f);
      for (int c = 74; c < 80; ++c) row[c] = 0.f;
    }
  }
  sZeroRow[tid] = 0.f;
  if (tid < 4) { sME[0][tid] = 0ull; sME[1][tid] = 0ull; }
  if (tid < 8) sTag[tid >> 2][tid & 3] = 0u;
  if (tid == 0) sWee = 0;
  // detect all-zero W_ee (true for this data; skipping a zero matmul is fp-exact)
  {
    bool any = false;
    const float4* p = (const float4*)g_Wee;
    for (int k = tid; k < (N_E * N_E) / 4; k += 256) {
      float4 x = p[k];
      any |= (x.x != 0.f) | (x.y != 0.f) | (x.z != 0.f) | (x.w != 0.f);
    }
    if (__ballot(any) != 0ull && lane == 0) sWee = 1;
  }
  __syncthreads();
  const int wee = sWee;

  // ---- per-thread state ----
  float vE = -65.f, ge = 0.f, gi = 0.f; int rE = 0;     // E neuron = tid
  float vI = -65.f, gI = 0.f; int rI = 0;               // I neuron = lane (replicated)
  float vO = -65.f, gO = 0.f, accO = 0.f; int rO = 0;   // output (replicated)

  unsigned long long mE = 0ull;   // own E word, s_e(t-1) (wave-local)
  unsigned long long mI = 0ull;   // I mask, s_i(t-1) (replicated in-register)

  // input + W0 prefetch pipeline (loads for step t issued at t-1)
  float cur = g_in[b * N_IN + lane];
  float n1  = g_in[((T > 1 ? 1 : 0) * BB + b) * N_IN + lane];

  unsigned long long mInC = __ballot(cur != 0.f);
  unsigned long long aRemC = 0ull;
  bool vaC[4] = {false, false, false, false};
  float fwC[4];
  if (mInC) {
    unsigned long long a = mInC;
    int ja[4];
#pragma unroll
    for (int k = 0; k < 4; ++k) {
      vaC[k] = (a != 0ull); ja[k] = vaC[k] ? (__ffsll(a) - 1) : 0; a &= (a - 1ull);
    }
    aRemC = a;
#pragma unroll
    for (int k = 0; k < 4; ++k) fwC[k] = g_W0[ja[k] * N_E + tid];
  }

  const int base64 = wav * 64;

  if (!wee) {
    // ================= HOT LOOP (no wee code at all) =================
    for (int t = 0; t < T; ++t) {
      const int slot = t & 1;
      const int tp = (t + 2 < T) ? (t + 2) : (T - 1);
      float n2 = g_in[(tp * BB + b) * N_IN + lane];   // prefetch t+2

      // ---- E-word gather FIRST: pEI/kow over own word of s_e(t-1) ----
      float pEI = 0.f, kow = 0.f;
      {
        unsigned long long e = mE;
        while (e) {
          const float* qb[4];
#pragma unroll
          for (int k = 0; k < 4; ++k) {
            bool v = (e != 0ull); int j = v ? (__ffsll(e) - 1) : 0; e &= (e - 1ull);
            qb[k] = v ? &sWeiO[(base64 + j) * 80] : sZeroRow;   // ONE base select
          }
          float fq[4], fr[4];
#pragma unroll
          for (int k = 0; k < 4; ++k) { fq[k] = qb[k][lane]; fr[k] = qb[k][colO]; }
#pragma unroll
          for (int k = 0; k < 4; ++k) pEI += fq[k];
#pragma unroll
          for (int k = 0; k < 4; ++k) kow += fr[k];
        }
      }

      // ---- EARLY publish + tag (data-before-tag via lgkmcnt drain) ----
      sP[slot][wav][lane] = pEI;
      if (lane < 16) sKo[slot][wav][lane] = kow;
      asm volatile("s_waitcnt lgkmcnt(0)" ::: "memory");
      if (lane == 0) *((volatile unsigned*)&sTag[slot][wav]) = (unsigned)(t + 1);

      // ---- kie gather over mI(t-1) ----
      float kie = 0.f;
      {
        unsigned long long c = mI;
        while (c) {
          const float* pb[8];
#pragma unroll
          for (int k = 0; k < 8; ++k) {
            bool v = (c != 0ull); int j = v ? (__ffsll(c) - 1) : 0; c &= (c - 1ull);
            pb[k] = v ? &sWie[j * N_E] : sZeroRow;
          }
          float fI[8];
#pragma unroll
          for (int k = 0; k < 8; ++k) fI[k] = pb[k][tid];
#pragma unroll
          for (int k = 0; k < 8; ++k) kie += fI[k];
        }
      }

      // ---- W0 consume (prefetched last iter; ascending) ----
      float kin = 0.f;
      if (mInC) {
#pragma unroll
        for (int k = 0; k < 4; ++k) kin += vaC[k] ? fmaxf(fwC[k], 0.f) : 0.f;
        while (aRemC) {
          int j = __ffsll(aRemC) - 1; aRemC &= (aRemC - 1ull);
          kin += fmaxf(g_W0[j * N_E + tid], 0.f);
        }
      }

      // ---- E LIF (COBA, C_m=1, g_L=0.05, ref=12) -> mE(t) ----
      ge = (ge + kin) * dA;           // kee == 0 exactly (wee false): (ge+kin)+0 == ge+kin
      gi = (gi + kie) * dG;
      {
        float t2 = ge * (0.f - vE);
        float t3 = gi * (-80.f - vE);
        float Itot = t2 + t3;
        float dv = 0.25f * ((-0.05f) * (vE - (-65.f)) + Itot);
        dv = dv * 0.0125f + dv * 0.9875f;      // _scale_grad forward (not fp-identity)
        vE = fmaxf(vE + dv, -200.f);
        rE = rE - 1; if (rE < 0) rE = 0;
        bool can = (rE == 0);
        bool sE = ((vE - (-50.f)) >= 0.f) && can;
        vE = (sE || !can) ? -65.f : vE;
        rE = sE ? 12 : rE;
        mE = __ballot(sE);
      }

      // ---- W0 prefetch for t+1 ----
      mInC = __ballot(n1 != 0.f);
      aRemC = 0ull;
      vaC[0] = vaC[1] = vaC[2] = vaC[3] = false;
      if (mInC) {
        unsigned long long a = mInC;
        int ja[4];
#pragma unroll
        for (int k = 0; k < 4; ++k) {
          vaC[k] = (a != 0ull); ja[k] = vaC[k] ? (__ffsll(a) - 1) : 0; a &= (a - 1ull);
        }
        aRemC = a;
#pragma unroll
        for (int k = 0; k < 4; ++k) fwC[k] = g_W0[ja[k] * N_E + tid];
      }

      // ---- poll tags (2 x b64 volatile reads of the aligned quad) ----
      {
        const unsigned want = (unsigned)(t + 1);
        const unsigned long long want2 = (((unsigned long long)want) << 32) | want;
        volatile unsigned long long* vt = (volatile unsigned long long*)&sTag[slot][0];
        while (true) {
          unsigned long long a0 = vt[0], a1 = vt[1];
          if (((a0 ^ want2) | (a1 ^ want2)) == 0ull) break;
        }
        asm volatile("" ::: "memory");
      }

      // ---- read partials ----
      float p0 = sP[slot][0][lane], p1 = sP[slot][1][lane];
      float p2 = sP[slot][2][lane], p3 = sP[slot][3][lane];
      float k0 = sKo[slot][0][col], k1 = sKo[slot][1][col];
      float k2 = sKo[slot][2][col], k3 = sKo[slot][3][col];

      // ---- I LIF (replicated; C_m=0.5, g_L=0.1, ref=6) -> mI(t) ----
      {
        float p = ((p0 + p1) + p2) + p3;
        gI = (gI + p) * dA;
        float Ii = gI * (0.f - vI);
        float dvi = 0.5f * ((-0.1f) * (vI - (-65.f)) + Ii);
        dvi = dvi * 0.0125f + dvi * 0.9875f;
        vI = fmaxf(vI + dvi, -200.f);
        rI = rI - 1; if (rI < 0) rI = 0;
        bool canI = (rI == 0);
        bool sI = ((vI - (-50.f)) >= 0.f) && canI;
        vI = (sI || !canI) ? -65.f : vI;
        rI = sI ? 6 : rI;
        mI = __ballot(sI);
      }

      // ---- O LIF (replicated, step t-1; iter 0 = exact fp no-op) ----
      {
        float ko = ((k0 + k1) + k2) + k3;
        gO = (gO + ko) * dA;
        float Io = gO * (0.f - vO);
        float dvo = 0.25f * ((-0.05f) * (vO - (-65.f)) + Io);
        dvo = dvo * 0.0125f + dvo * 0.9875f;
        vO = fmaxf(vO + dvo, -200.f);
        rO = rO - 1; if (rO < 0) rO = 0;
        bool canO = (rO == 0);
        bool sO = ((vO - (-50.f)) >= 0.f) && canO;
        vO = (sO || !canO) ? -65.f : vO;
        rO = sO ? 12 : rO;
        accO += sO ? 1.f : 0.f;
      }

      cur = n1; n1 = n2;
    }
  } else {
    // ================= FALLBACK LOOP (wee != 0; full r11 body) =================
    unsigned long long we0 = 0ull, we1 = 0ull, we2 = 0ull, we3 = 0ull;
    for (int t = 0; t < T; ++t) {
      const int slot = t & 1;
      const int tp = (t + 2 < T) ? (t + 2) : (T - 1);
      float n2 = g_in[(tp * BB + b) * N_IN + lane];

      float pEI = 0.f, kow = 0.f;
      {
        unsigned long long e = mE;
        while (e) {
          const float* qb[4];
#pragma unroll
          for (int k = 0; k < 4; ++k) {
            bool v = (e != 0ull); int j = v ? (__ffsll(e) - 1) : 0; e &= (e - 1ull);
            qb[k] = v ? &sWeiO[(base64 + j) * 80] : sZeroRow;
          }
          float fq[4], fr[4];
#pragma unroll
          for (int k = 0; k < 4; ++k) { fq[k] = qb[k][lane]; fr[k] = qb[k][colO]; }
#pragma unroll
          for (int k = 0; k < 4; ++k) pEI += fq[k];
#pragma unroll
          for (int k = 0; k < 4; ++k) kow += fr[k];
        }
      }
      sP[slot][wav][lane] = pEI;
      if (lane < 16) sKo[slot][wav][lane] = kow;
      asm volatile("s_waitcnt lgkmcnt(0)" ::: "memory");
      if (lane == 0) *((volatile unsigned*)&sTag[slot][wav]) = (unsigned)(t + 1);

      float kie = 0.f;
      {
        unsigned long long c = mI;
        while (c) {
          const float* pb[8];
#pragma unroll
          for (int k = 0; k < 8; ++k) {
            bool v = (c != 0ull); int j = v ? (__ffsll(c) - 1) : 0; c &= (c - 1ull);
            pb[k] = v ? &sWie[j * N_E] : sZeroRow;
          }
          float fI[8];
#pragma unroll
          for (int k = 0; k < 8; ++k) fI[k] = pb[k][tid];
#pragma unroll
          for (int k = 0; k < 8; ++k) kie += fI[k];
        }
      }

      float kin = 0.f;
      if (mInC) {
#pragma unroll
        for (int k = 0; k < 4; ++k) kin += vaC[k] ? fmaxf(fwC[k], 0.f) : 0.f;
        while (aRemC) {
          int j = __ffsll(aRemC) - 1; aRemC &= (aRemC - 1ull);
          kin += fmaxf(g_W0[j * N_E + tid], 0.f);
        }
      }

      float kee = 0.f;
      {
        unsigned long long m0 = we0, m1 = we1, m2 = we2, m3 = we3;
        while (m0 | m1 | m2 | m3) {
          bool h0 = (m0 != 0ull), h1 = (m1 != 0ull), h2 = (m2 != 0ull), h3 = (m3 != 0ull);
          int idx = 0;
          if (h0)      { idx = __ffsll(m0) - 1;       m0 &= (m0 - 1ull); }
          else if (h1) { idx = 64 + __ffsll(m1) - 1;  m1 &= (m1 - 1ull); }
          else if (h2) { idx = 128 + __ffsll(m2) - 1; m2 &= (m2 - 1ull); }
          else if (h3) { idx = 192 + __ffsll(m3) - 1; m3 &= (m3 - 1ull); }
          kee += g_Wee[idx * N_E + tid];
        }
      }

      ge = ((ge + kin) + kee) * dA;
      gi = (gi + kie) * dG;
      {
        float t2 = ge * (0.f - vE);
        float t3 = gi * (-80.f - vE);
        float Itot = t2 + t3;
        float dv = 0.25f * ((-0.05f) * (vE - (-65.f)) + Itot);
        dv = dv * 0.0125f + dv * 0.9875f;
        vE = fmaxf(vE + dv, -200.f);
        rE = rE - 1; if (rE < 0) rE = 0;
        bool can = (rE == 0);
        bool sE = ((vE - (-50.f)) >= 0.f) && can;
        vE = (sE || !can) ? -65.f : vE;
        rE = sE ? 12 : rE;
        unsigned long long fresh = __ballot(sE);
        if (lane == 0) sME[slot][wav] = fresh;
        mE = fresh;
      }

      mInC = __ballot(n1 != 0.f);
      aRemC = 0ull;
      vaC[0] = vaC[1] = vaC[2] = vaC[3] = false;
      if (mInC) {
        unsigned long long a = mInC;
        int ja[4];
#pragma unroll
        for (int k = 0; k < 4; ++k) {
          vaC[k] = (a != 0ull); ja[k] = vaC[k] ? (__ffsll(a) - 1) : 0; a &= (a - 1ull);
        }
        aRemC = a;
#pragma unroll
        for (int k = 0; k < 4; ++k) fwC[k] = g_W0[ja[k] * N_E + tid];
      }

      {
        const unsigned want = (unsigned)(t + 1);
        const unsigned long long want2 = (((unsigned long long)want) << 32) | want;
        volatile unsigned long long* vt = (volatile unsigned long long*)&sTag[slot][0];
        while (true) {
          unsigned long long a0 = vt[0], a1 = vt[1];
          if (((a0 ^ want2) | (a1 ^ want2)) == 0ull) break;
        }
        asm volatile("" ::: "memory");
      }

      float p0 = sP[slot][0][lane], p1 = sP[slot][1][lane];
      float p2 = sP[slot][2][lane], p3 = sP[slot][3][lane];
      float k0 = sKo[slot][0][col], k1 = sKo[slot][1][col];
      float k2 = sKo[slot][2][col], k3 = sKo[slot][3][col];

      {
        float p = ((p0 + p1) + p2) + p3;
        gI = (gI + p) * dA;
        float Ii = gI * (0.f - vI);
        float dvi = 0.5f * ((-0.1f) * (vI - (-65.f)) + Ii);
        dvi = dvi * 0.0125f + dvi * 0.9875f;
        vI = fmaxf(vI + dvi, -200.f);
        rI = rI - 1; if (rI < 0) rI = 0;
        bool canI = (rI == 0);
        bool sI = ((vI - (-50.f)) >= 0.f) && canI;
        vI = (sI || !canI) ? -65.f : vI;
        rI = sI ? 6 : rI;
        mI = __ballot(sI);
      }

      {
        float ko = ((k0 + k1) + k2) + k3;
        gO = (gO + ko) * dA;
        float Io = gO * (0.f - vO);
        float dvo = 0.25f * ((-0.05f) * (vO - (-65.f)) + Io);
        dvo = dvo * 0.0125f + dvo * 0.9875f;
        vO = fmaxf(vO + dvo, -200.f);
        rO = rO - 1; if (rO < 0) rO = 0;
        bool canO = (rO == 0);
        bool sO = ((vO - (-50.f)) >= 0.f) && canO;
        vO = (sO || !canO) ? -65.f : vO;
        rO = sO ? 12 : rO;
        accO += sO ? 1.f : 0.f;
      }

      __syncthreads();   // fallback path: make sME visible
      we0 = rfl64(sME[slot][0]); we1 = rfl64(sME[slot][1]);
      we2 = rfl64(sME[slot][2]); we3 = rfl64(sME[slot][3]);

      cur = n1; n1 = n2;
    }
  }

  // ---- drain: O step T-1 over s_e(T-1) (own word in mE) ----
  {
    float kd = 0.f;
    unsigned long long e = mE;
    while (e) {
      const float* rb[4];
#pragma unroll
      for (int k = 0; k < 4; ++k) {
        bool v = (e != 0ull); int j = v ? (__ffsll(e) - 1) : 0; e &= (e - 1ull);
        rb[k] = v ? &sWeiO[(base64 + j) * 80] : sZeroRow;
      }
      float fr[4];
#pragma unroll
      for (int k = 0; k < 4; ++k) fr[k] = rb[k][colO];
#pragma unroll
      for (int k = 0; k < 4; ++k) kd += fr[k];
    }
    __syncthreads();
    sP[0][wav][lane] = kd;
    __syncthreads();
    float ko = ((sP[0][0][col] + sP[0][1][col]) + sP[0][2][col]) + sP[0][3][col];
    gO = (gO + ko) * dA;
    float Io = gO * (0.f - vO);
    float dvo = 0.25f * ((-0.05f) * (vO - (-65.f)) + Io);
    dvo = dvo * 0.0125f + dvo * 0.9875f;
    vO = fmaxf(vO + dvo, -200.f);
    rO = rO - 1; if (rO < 0) rO = 0;
    bool canO = (rO == 0);
    bool sO = ((vO - (-50.f)) >= 0.f) && canO;
    accO += sO ? 1.f : 0.f;
  }

  if (wav == 0 && lane < N_OUT) g_out[b * N_OUT + lane] = accO;
}

extern "C" void kernel_launch(void* const* d_in, const int* in_sizes, int n_in,
                              void* d_out, int out_size, void* d_ws, size_t ws_size,
                              hipStream_t stream) {
  const float* g_in  = (const float*)d_in[0];
  const float* g_W0  = (const float*)d_in[1];
  const float* g_W1  = (const float*)d_in[2];
  const float* g_Wee = (const float*)d_in[3];
  const float* g_Wei = (const float*)d_in[4];
  const float* g_Wie = (const float*)d_in[5];
  float* out = (float*)d_out;
  int T = in_sizes[0] / (BB * N_IN);
  float dA = (float)exp(-0.25 / 2.0);   // tau_ampa = 2.0
  float dG = (float)exp(-0.25 / 9.0);   // tau_gaba = 9.0
  ping_kernel<<<dim3(BB), dim3(256), 0, stream>>>(g_in, g_W0, g_W1, g_Wee, g_Wei, g_Wie, out, T, dA, dG);
}

// Round 14
// 4770.238 us; speedup vs baseline: 1.2557x; 1.0253x over previous
//
#include <hip/hip_runtime.h>
#include <math.h>

#pragma clang fp contract(off)

#define BB 64      // batch
#define N_IN 64
#define N_E 256
#define N_I 64
#define N_OUT 10

__device__ inline unsigned long long rfl64(unsigned long long x) {
  unsigned int lo = __builtin_amdgcn_readfirstlane((unsigned int)x);
  unsigned int hi = __builtin_amdgcn_readfirstlane((unsigned int)(x >> 32));
  return (((unsigned long long)hi) << 32) | (unsigned long long)lo;
}

// r13 (bit-exact, 4.89 ms) with three serial-LDS-event cuts:
//  (1) NO lgkmcnt drain before the tag write: DS ops from one wave complete
//      IN ORDER (the property that lets the compiler emit fine-grained
//      lgkmcnt(N) between ds_reads — m97 asm), so the tag, issued after the
//      partial writes, cannot land before them. A zero-instruction compiler
//      barrier prevents IR reordering; hardware order does the rest.
//  (2) EARLY TAG PROBE: volatile tag reads issue right after our tag write;
//      their latency overlaps kie/W0/E-LIF. If the probe already shows t+1
//      at the consume point (expected — tags publish early), the poll's
//      dependent read is skipped entirely. Fallback poll = r13's.
//  (3) TRANSPOSED PARTIALS sPK[slot][lane][4] / sKoT[slot][col][4]: post-poll
//      read is ONE ds_read_b128 per consumer instead of 4 b32s. Component w
//      = wave w, so ((x+y)+z)+w == ((p0+p1)+p2)+p3 — byte-identical order.
// Everything else (gathers, LIF sequences, slot protocol, delayed-O, W0
// bottom prefetch, merged Wei||W1 table) is identical to bit-exact r13.
__global__ __launch_bounds__(256, 1) void ping_kernel(
    const float* __restrict__ g_in,   // [T,64,64]
    const float* __restrict__ g_W0,   // [64,256]  clamp >=0 at use
    const float* __restrict__ g_W1,   // [256,10]  clamp >=0 at stage
    const float* __restrict__ g_Wee,  // [256,256]
    const float* __restrict__ g_Wei,  // [256,64]
    const float* __restrict__ g_Wie,  // [64,256]
    float* __restrict__ g_out,        // [64,10]
    int T, float dA, float dG)
{
  const int tid  = threadIdx.x;
  const int lane = tid & 63;
  const int wav  = tid >> 6;
  const int b    = blockIdx.x;
  const int col  = (lane < N_OUT) ? lane : 0;
  const int colO = 64 + col;                 // W1 column inside merged row

  __shared__ float sWie[N_I * N_E];          // 64 KB  [j][e]
  __shared__ float sWeiO[N_E * 80];          // 80 KB  [j][0:64)=Wei, [64:74)=W1
  __shared__ float sZeroRow[256];            // 1 KB zero row
  __shared__ __align__(16) float sPK[2][64][4];   // E->I partials [slot][lane][wave]
  __shared__ __align__(16) float sKoT[2][16][4];  // E->O partials [slot][col][wave]
  __shared__ __align__(16) unsigned sTag[2][4];   // publish tags (16B quads)
  __shared__ unsigned long long sME[2][4];   // E masks (wee fallback only)
  __shared__ int sWee;

  // ---- one-time staging ----
  {
    const float4* s0 = (const float4*)g_Wie; float4* d0 = (float4*)sWie;
    for (int k = tid; k < (N_I * N_E) / 4; k += 256) d0[k] = s0[k];
    {
      int j = tid;
      float* row = &sWeiO[j * 80];
      for (int c = 0; c < 64; ++c) row[c] = g_Wei[j * N_I + c];
      for (int o = 0; o < N_OUT; ++o) row[64 + o] = fmaxf(g_W1[j * N_OUT + o], 0.f);
      for (int c = 74; c < 80; ++c) row[c] = 0.f;
    }
  }
  sZeroRow[tid] = 0.f;
  if (tid < 4) { sME[0][tid] = 0ull; sME[1][tid] = 0ull; }
  if (tid < 8) sTag[tid >> 2][tid & 3] = 0u;
  if (tid == 0) sWee = 0;
  // detect all-zero W_ee (true for this data; skipping a zero matmul is fp-exact)
  {
    bool any = false;
    const float4* p = (const float4*)g_Wee;
    for (int k = tid; k < (N_E * N_E) / 4; k += 256) {
      float4 x = p[k];
      any |= (x.x != 0.f) | (x.y != 0.f) | (x.z != 0.f) | (x.w != 0.f);
    }
    if (__ballot(any) != 0ull && lane == 0) sWee = 1;
  }
  __syncthreads();
  const int wee = sWee;

  // ---- per-thread state ----
  float vE = -65.f, ge = 0.f, gi = 0.f; int rE = 0;     // E neuron = tid
  float vI = -65.f, gI = 0.f; int rI = 0;               // I neuron = lane (replicated)
  float vO = -65.f, gO = 0.f, accO = 0.f; int rO = 0;   // output (replicated)

  unsigned long long mE = 0ull;   // own E word, s_e(t-1) (wave-local)
  unsigned long long mI = 0ull;   // I mask, s_i(t-1) (replicated in-register)

  // input + W0 prefetch pipeline (loads for step t issued at t-1)
  float cur = g_in[b * N_IN + lane];
  float n1  = g_in[((T > 1 ? 1 : 0) * BB + b) * N_IN + lane];

  unsigned long long mInC = __ballot(cur != 0.f);
  unsigned long long aRemC = 0ull;
  bool vaC[4] = {false, false, false, false};
  float fwC[4];
  if (mInC) {
    unsigned long long a = mInC;
    int ja[4];
#pragma unroll
    for (int k = 0; k < 4; ++k) {
      vaC[k] = (a != 0ull); ja[k] = vaC[k] ? (__ffsll(a) - 1) : 0; a &= (a - 1ull);
    }
    aRemC = a;
#pragma unroll
    for (int k = 0; k < 4; ++k) fwC[k] = g_W0[ja[k] * N_E + tid];
  }

  const int base64 = wav * 64;

  if (!wee) {
    // ================= HOT LOOP =================
    for (int t = 0; t < T; ++t) {
      const int slot = t & 1;
      const int tp = (t + 2 < T) ? (t + 2) : (T - 1);
      float n2 = g_in[(tp * BB + b) * N_IN + lane];   // prefetch t+2

      // ---- E-word gather: pEI/kow over own word of s_e(t-1) ----
      float pEI = 0.f, kow = 0.f;
      {
        unsigned long long e = mE;
        while (e) {
          const float* qb[4];
#pragma unroll
          for (int k = 0; k < 4; ++k) {
            bool v = (e != 0ull); int j = v ? (__ffsll(e) - 1) : 0; e &= (e - 1ull);
            qb[k] = v ? &sWeiO[(base64 + j) * 80] : sZeroRow;
          }
          float fq[4], fr[4];
#pragma unroll
          for (int k = 0; k < 4; ++k) { fq[k] = qb[k][lane]; fr[k] = qb[k][colO]; }
#pragma unroll
          for (int k = 0; k < 4; ++k) pEI += fq[k];
#pragma unroll
          for (int k = 0; k < 4; ++k) kow += fr[k];
        }
      }

      // ---- publish partials, then tag (DS in-order; compiler barrier only) ----
      sPK[slot][lane][wav] = pEI;
      if (lane < 16) sKoT[slot][lane][wav] = kow;
      asm volatile("" ::: "memory");   // no IR reordering; HW DS order does the rest
      if (lane == 0) *((volatile unsigned*)&sTag[slot][wav]) = (unsigned)(t + 1);

      // ---- EARLY PROBE: issue tag reads now; latency hides under the body ----
      unsigned long long pr0 = ((volatile unsigned long long*)&sTag[slot][0])[0];
      unsigned long long pr1 = ((volatile unsigned long long*)&sTag[slot][0])[1];

      // ---- kie gather over mI(t-1) ----
      float kie = 0.f;
      {
        unsigned long long c = mI;
        while (c) {
          const float* pb[8];
#pragma unroll
          for (int k = 0; k < 8; ++k) {
            bool v = (c != 0ull); int j = v ? (__ffsll(c) - 1) : 0; c &= (c - 1ull);
            pb[k] = v ? &sWie[j * N_E] : sZeroRow;
          }
          float fI[8];
#pragma unroll
          for (int k = 0; k < 8; ++k) fI[k] = pb[k][tid];
#pragma unroll
          for (int k = 0; k < 8; ++k) kie += fI[k];
        }
      }

      // ---- W0 consume (prefetched last iter; ascending) ----
      float kin = 0.f;
      if (mInC) {
#pragma unroll
        for (int k = 0; k < 4; ++k) kin += vaC[k] ? fmaxf(fwC[k], 0.f) : 0.f;
        while (aRemC) {
          int j = __ffsll(aRemC) - 1; aRemC &= (aRemC - 1ull);
          kin += fmaxf(g_W0[j * N_E + tid], 0.f);
        }
      }

      // ---- E LIF (COBA, C_m=1, g_L=0.05, ref=12) -> mE(t) ----
      ge = (ge + kin) * dA;           // kee == 0 exactly (wee false)
      gi = (gi + kie) * dG;
      {
        float t2 = ge * (0.f - vE);
        float t3 = gi * (-80.f - vE);
        float Itot = t2 + t3;
        float dv = 0.25f * ((-0.05f) * (vE - (-65.f)) + Itot);
        dv = dv * 0.0125f + dv * 0.9875f;      // _scale_grad forward (not fp-identity)
        vE = fmaxf(vE + dv, -200.f);
        rE = rE - 1; if (rE < 0) rE = 0;
        bool can = (rE == 0);
        bool sE = ((vE - (-50.f)) >= 0.f) && can;
        vE = (sE || !can) ? -65.f : vE;
        rE = sE ? 12 : rE;
        mE = __ballot(sE);
      }

      // ---- W0 prefetch for t+1 ----
      mInC = __ballot(n1 != 0.f);
      aRemC = 0ull;
      vaC[0] = vaC[1] = vaC[2] = vaC[3] = false;
      if (mInC) {
        unsigned long long a = mInC;
        int ja[4];
#pragma unroll
        for (int k = 0; k < 4; ++k) {
          vaC[k] = (a != 0ull); ja[k] = vaC[k] ? (__ffsll(a) - 1) : 0; a &= (a - 1ull);
        }
        aRemC = a;
#pragma unroll
        for (int k = 0; k < 4; ++k) fwC[k] = g_W0[ja[k] * N_E + tid];
      }

      // ---- probe check; poll fallback only if stale ----
      {
        const unsigned want = (unsigned)(t + 1);
        const unsigned long long want2 = (((unsigned long long)want) << 32) | want;
        if ((((pr0 ^ want2) | (pr1 ^ want2))) != 0ull) {
          volatile unsigned long long* vt = (volatile unsigned long long*)&sTag[slot][0];
          while (true) {
            unsigned long long a0 = vt[0], a1 = vt[1];
            if (((a0 ^ want2) | (a1 ^ want2)) == 0ull) break;
          }
        }
        asm volatile("" ::: "memory");
      }

      // ---- read partials: ONE b128 each ----
      float4 P = *(const float4*)&sPK[slot][lane][0];
      float4 K = *(const float4*)&sKoT[slot][col][0];

      // ---- I LIF (replicated; C_m=0.5, g_L=0.1, ref=6) -> mI(t) ----
      {
        float p = ((P.x + P.y) + P.z) + P.w;
        gI = (gI + p) * dA;
        float Ii = gI * (0.f - vI);
        float dvi = 0.5f * ((-0.1f) * (vI - (-65.f)) + Ii);
        dvi = dvi * 0.0125f + dvi * 0.9875f;
        vI = fmaxf(vI + dvi, -200.f);
        rI = rI - 1; if (rI < 0) rI = 0;
        bool canI = (rI == 0);
        bool sI = ((vI - (-50.f)) >= 0.f) && canI;
        vI = (sI || !canI) ? -65.f : vI;
        rI = sI ? 6 : rI;
        mI = __ballot(sI);
      }

      // ---- O LIF (replicated, step t-1; iter 0 = exact fp no-op) ----
      {
        float ko = ((K.x + K.y) + K.z) + K.w;
        gO = (gO + ko) * dA;
        float Io = gO * (0.f - vO);
        float dvo = 0.25f * ((-0.05f) * (vO - (-65.f)) + Io);
        dvo = dvo * 0.0125f + dvo * 0.9875f;
        vO = fmaxf(vO + dvo, -200.f);
        rO = rO - 1; if (rO < 0) rO = 0;
        bool canO = (rO == 0);
        bool sO = ((vO - (-50.f)) >= 0.f) && canO;
        vO = (sO || !canO) ? -65.f : vO;
        rO = sO ? 12 : rO;
        accO += sO ? 1.f : 0.f;
      }

      cur = n1; n1 = n2;
    }
  } else {
    // ============ FALLBACK LOOP (wee != 0; conservative protocol) ============
    unsigned long long we0 = 0ull, we1 = 0ull, we2 = 0ull, we3 = 0ull;
    for (int t = 0; t < T; ++t) {
      const int slot = t & 1;
      const int tp = (t + 2 < T) ? (t + 2) : (T - 1);
      float n2 = g_in[(tp * BB + b) * N_IN + lane];

      float pEI = 0.f, kow = 0.f;
      {
        unsigned long long e = mE;
        while (e) {
          const float* qb[4];
#pragma unroll
          for (int k = 0; k < 4; ++k) {
            bool v = (e != 0ull); int j = v ? (__ffsll(e) - 1) : 0; e &= (e - 1ull);
            qb[k] = v ? &sWeiO[(base64 + j) * 80] : sZeroRow;
          }
          float fq[4], fr[4];
#pragma unroll
          for (int k = 0; k < 4; ++k) { fq[k] = qb[k][lane]; fr[k] = qb[k][colO]; }
#pragma unroll
          for (int k = 0; k < 4; ++k) pEI += fq[k];
#pragma unroll
          for (int k = 0; k < 4; ++k) kow += fr[k];
        }
      }
      sPK[slot][lane][wav] = pEI;
      if (lane < 16) sKoT[slot][lane][wav] = kow;
      asm volatile("s_waitcnt lgkmcnt(0)" ::: "memory");
      if (lane == 0) *((volatile unsigned*)&sTag[slot][wav]) = (unsigned)(t + 1);

      float kie = 0.f;
      {
        unsigned long long c = mI;
        while (c) {
          const float* pb[8];
#pragma unroll
          for (int k = 0; k < 8; ++k) {
            bool v = (c != 0ull); int j = v ? (__ffsll(c) - 1) : 0; c &= (c - 1ull);
            pb[k] = v ? &sWie[j * N_E] : sZeroRow;
          }
          float fI[8];
#pragma unroll
          for (int k = 0; k < 8; ++k) fI[k] = pb[k][tid];
#pragma unroll
          for (int k = 0; k < 8; ++k) kie += fI[k];
        }
      }

      float kin = 0.f;
      if (mInC) {
#pragma unroll
        for (int k = 0; k < 4; ++k) kin += vaC[k] ? fmaxf(fwC[k], 0.f) : 0.f;
        while (aRemC) {
          int j = __ffsll(aRemC) - 1; aRemC &= (aRemC - 1ull);
          kin += fmaxf(g_W0[j * N_E + tid], 0.f);
        }
      }

      float kee = 0.f;
      {
        unsigned long long m0 = we0, m1 = we1, m2 = we2, m3 = we3;
        while (m0 | m1 | m2 | m3) {
          bool h0 = (m0 != 0ull), h1 = (m1 != 0ull), h2 = (m2 != 0ull), h3 = (m3 != 0ull);
          int idx = 0;
          if (h0)      { idx = __ffsll(m0) - 1;       m0 &= (m0 - 1ull); }
          else if (h1) { idx = 64 + __ffsll(m1) - 1;  m1 &= (m1 - 1ull); }
          else if (h2) { idx = 128 + __ffsll(m2) - 1; m2 &= (m2 - 1ull); }
          else if (h3) { idx = 192 + __ffsll(m3) - 1; m3 &= (m3 - 1ull); }
          kee += g_Wee[idx * N_E + tid];
        }
      }

      ge = ((ge + kin) + kee) * dA;
      gi = (gi + kie) * dG;
      {
        float t2 = ge * (0.f - vE);
        float t3 = gi * (-80.f - vE);
        float Itot = t2 + t3;
        float dv = 0.25f * ((-0.05f) * (vE - (-65.f)) + Itot);
        dv = dv * 0.0125f + dv * 0.9875f;
        vE = fmaxf(vE + dv, -200.f);
        rE = rE - 1; if (rE < 0) rE = 0;
        bool can = (rE == 0);
        bool sE = ((vE - (-50.f)) >= 0.f) && can;
        vE = (sE || !can) ? -65.f : vE;
        rE = sE ? 12 : rE;
        unsigned long long fresh = __ballot(sE);
        if (lane == 0) sME[slot][wav] = fresh;
        mE = fresh;
      }

      mInC = __ballot(n1 != 0.f);
      aRemC = 0ull;
      vaC[0] = vaC[1] = vaC[2] = vaC[3] = false;
      if (mInC) {
        unsigned long long a = mInC;
        int ja[4];
#pragma unroll
        for (int k = 0; k < 4; ++k) {
          vaC[k] = (a != 0ull); ja[k] = vaC[k] ? (__ffsll(a) - 1) : 0; a &= (a - 1ull);
        }
        aRemC = a;
#pragma unroll
        for (int k = 0; k < 4; ++k) fwC[k] = g_W0[ja[k] * N_E + tid];
      }

      {
        const unsigned want = (unsigned)(t + 1);
        const unsigned long long want2 = (((unsigned long long)want) << 32) | want;
        volatile unsigned long long* vt = (volatile unsigned long long*)&sTag[slot][0];
        while (true) {
          unsigned long long a0 = vt[0], a1 = vt[1];
          if (((a0 ^ want2) | (a1 ^ want2)) == 0ull) break;
        }
        asm volatile("" ::: "memory");
      }

      float4 P = *(const float4*)&sPK[slot][lane][0];
      float4 K = *(const float4*)&sKoT[slot][col][0];

      {
        float p = ((P.x + P.y) + P.z) + P.w;
        gI = (gI + p) * dA;
        float Ii = gI * (0.f - vI);
        float dvi = 0.5f * ((-0.1f) * (vI - (-65.f)) + Ii);
        dvi = dvi * 0.0125f + dvi * 0.9875f;
        vI = fmaxf(vI + dvi, -200.f);
        rI = rI - 1; if (rI < 0) rI = 0;
        bool canI = (rI == 0);
        bool sI = ((vI - (-50.f)) >= 0.f) && canI;
        vI = (sI || !canI) ? -65.f : vI;
        rI = sI ? 6 : rI;
        mI = __ballot(sI);
      }

      {
        float ko = ((K.x + K.y) + K.z) + K.w;
        gO = (gO + ko) * dA;
        float Io = gO * (0.f - vO);
        float dvo = 0.25f * ((-0.05f) * (vO - (-65.f)) + Io);
        dvo = dvo * 0.0125f + dvo * 0.9875f;
        vO = fmaxf(vO + dvo, -200.f);
        rO = rO - 1; if (rO < 0) rO = 0;
        bool canO = (rO == 0);
        bool sO = ((vO - (-50.f)) >= 0.f) && canO;
        vO = (sO || !canO) ? -65.f : vO;
        rO = sO ? 12 : rO;
        accO += sO ? 1.f : 0.f;
      }

      __syncthreads();   // fallback path: make sME visible
      we0 = rfl64(sME[slot][0]); we1 = rfl64(sME[slot][1]);
      we2 = rfl64(sME[slot][2]); we3 = rfl64(sME[slot][3]);

      cur = n1; n1 = n2;
    }
  }

  // ---- drain: O step T-1 over s_e(T-1) (own word in mE) ----
  {
    float kd = 0.f;
    unsigned long long e = mE;
    while (e) {
      const float* rb[4];
#pragma unroll
      for (int k = 0; k < 4; ++k) {
        bool v = (e != 0ull); int j = v ? (__ffsll(e) - 1) : 0; e &= (e - 1ull);
        rb[k] = v ? &sWeiO[(base64 + j) * 80] : sZeroRow;
      }
      float fr[4];
#pragma unroll
      for (int k = 0; k < 4; ++k) fr[k] = rb[k][colO];
#pragma unroll
      for (int k = 0; k < 4; ++k) kd += fr[k];
    }
    __syncthreads();
    if (lane < 16) sKoT[0][lane][wav] = kd;
    __syncthreads();
    float4 K = *(const float4*)&sKoT[0][col][0];
    float ko = ((K.x + K.y) + K.z) + K.w;
    gO = (gO + ko) * dA;
    float Io = gO * (0.f - vO);
    float dvo = 0.25f * ((-0.05f) * (vO - (-65.f)) + Io);
    dvo = dvo * 0.0125f + dvo * 0.9875f;
    vO = fmaxf(vO + dvo, -200.f);
    rO = rO - 1; if (rO < 0) rO = 0;
    bool canO = (rO == 0);
    bool sO = ((vO - (-50.f)) >= 0.f) && canO;
    accO += sO ? 1.f : 0.f;
  }

  if (wav == 0 && lane < N_OUT) g_out[b * N_OUT + lane] = accO;
}

extern "C" void kernel_launch(void* const* d_in, const int* in_sizes, int n_in,
                              void* d_out, int out_size, void* d_ws, size_t ws_size,
                              hipStream_t stream) {
  const float* g_in  = (const float*)d_in[0];
  const float* g_W0  = (const float*)d_in[1];
  const float* g_W1  = (const float*)d_in[2];
  const float* g_Wee = (const float*)d_in[3];
  const float* g_Wei = (const float*)d_in[4];
  const float* g_Wie = (const float*)d_in[5];
  float* out = (float*)d_out;
  int T = in_sizes[0] / (BB * N_IN);
  float dA = (float)exp(-0.25 / 2.0);   // tau_ampa = 2.0
  float dG = (float)exp(-0.25 / 9.0);   // tau_gaba = 9.0
  ping_kernel<<<dim3(BB), dim3(256), 0, stream>>>(g_in, g_W0, g_W1, g_Wee, g_Wei, g_Wie, out, T, dA, dG);
}